// Round 8
// baseline (575.695 us; speedup 1.0000x reference)
//
#include <hip/hip_runtime.h>

// KNN k-th smallest distance, v6: FLIPPED dataflow.
// dist = sqrt(2 - 2*dot(zn,rn)); sorted(dist)[k] == (k+1)-th LARGEST dot.
//
// Rounds 5-7 were pinned at the L3 wall: every q-tile block re-read all of B
// (refs) -> 410 MB/pass from Infinity Cache (~6.5 TB/s observed). Fix: hold
// the REFS in registers (32 refs/wave as resident MFMA A-fragments) and
// stream the QUERIES (0.5 MB total -> L2-resident on every XCD). The 12.8 MB
// ref matrix is read ONCE per pass; the 410 MB stream comes from L2.
//
//  1) normalize_bf16: fused z+ref rows -> L2-normalized bf16
//  2) knn_pass<1>: per (32-ref tile, q) subset max -> maxes[tile][q] (col-major,
//     coalesced via per-wave LDS buffer)
//  3) knn_threshold: per q, group tiles into 64 groups (ti%64); group max is a
//     real dot; (k+1)-th largest of the 64 group maxes is a valid lower bound
//     T <= true (k+1)-th largest dot. Also zeroes survivor counters.
//  4) knn_pass<2>: recompute dots, keep v >= T[q] via rare atomic append
//  5) knn_final: exact (k+1)-th largest of survivors -> dist
//
// Pass kernels: 64-thread (single-wave) blocks, grid 1563 tiles x 2 q-halves
// = 3126 blocks ~ 12.2 waves/CU, ALL co-resident (no tail), no barriers.
// NO __launch_bounds__ min-waves (round 4: it caps the UNIFIED VGPR+AGPR
// budget and spills to scratch).

#define D_DIM 128
#define KK 11          // top-11 (k=10 -> 11th largest)
#define CAP 1024       // survivor capacity per row

typedef __bf16 bf16_t;
typedef bf16_t bf16x8 __attribute__((ext_vector_type(8)));
typedef float f32x4 __attribute__((ext_vector_type(4)));

__device__ __forceinline__ unsigned short f2bf(float f) {
    unsigned u = __float_as_uint(f);
    return (unsigned short)((u + 0x7fffu + ((u >> 16) & 1u)) >> 16);  // RNE
}

__device__ __forceinline__ void insert11(float (&b)[KK], float v) {
    // b sorted ascending; b[0] = 11th-largest so far.
    if (v > b[0]) {
        b[0] = v;
        #pragma unroll
        for (int i = 0; i < KK - 1; ++i) {
            float lo = fminf(b[i], b[i + 1]);
            float hi = fmaxf(b[i], b[i + 1]);
            b[i] = lo;
            b[i + 1] = hi;
        }
    }
}

__global__ __launch_bounds__(256) void normalize_bf16(
    const float* __restrict__ z, const float* __restrict__ ref,
    unsigned short* __restrict__ zb, unsigned short* __restrict__ rb,
    int N, int M)
{
    const int w = threadIdx.x >> 6;
    const int l = threadIdx.x & 63;
    const int row = blockIdx.x * 4 + w;
    if (row >= N + M) return;
    const float* in; unsigned short* out; int r;
    if (row < N) { in = z;   out = zb; r = row; }
    else         { in = ref; out = rb; r = row - N; }
    const float2 v = ((const float2*)in)[(size_t)r * 64 + l];
    float ss = v.x * v.x + v.y * v.y;
    #pragma unroll
    for (int off = 32; off > 0; off >>= 1) ss += __shfl_xor(ss, off);
    const float inv = rsqrtf(ss);
    ushort2 o; o.x = f2bf(v.x * inv); o.y = f2bf(v.y * inv);
    ((ushort2*)out)[(size_t)r * 64 + l] = o;
}

// One wave per block. Wave owns refs [ti*32, ti*32+32) as resident A-frags and
// streams queries of its q-half as B-frags (2-stage ping-pong, no barriers).
// PASS==1: subset max per q -> LDS buffer -> coalesced col-major writeout.
// PASS==2: filter vs T[q], atomic append of rare survivors.
template <int PASS>
__global__ __launch_bounds__(64) void knn_pass(
    const unsigned short* __restrict__ zb, const unsigned short* __restrict__ rb,
    float* __restrict__ maxes, const float* __restrict__ T,
    int* __restrict__ cnt, float* __restrict__ surv,
    int N, int M, int nt32)
{
    __shared__ float mbuf[1024];   // PASS1 subset-max buffer (q-half = 1024 rows)

    const int lane = threadIdx.x;
    const int quad = lane >> 4;
    const int ln = lane & 15;
    const int ti = blockIdx.x >> 1;        // 32-ref tile id
    const int qs = blockIdx.x & 1;         // q half
    const int r0 = ti * 32;
    const int q0 = qs * (N >> 1);
    const int niter = (N >> 1) >> 4;       // 64 q-tiles of 16

    // Resident A-frags (refs): lane (ln,quad) holds A[m=ln][k=quad*8+j] for
    // ref r0+rt*16+ln, k-step ks. Tail tile overreads <=16 rows past M into
    // the maxes region of d_ws (garbage, masked at epilogue).
    bf16x8 arf[2][4];
    #pragma unroll
    for (int rt = 0; rt < 2; ++rt)
        #pragma unroll
        for (int ks = 0; ks < 4; ++ks)
            arf[rt][ks] = *(const bf16x8*)
                &rb[(size_t)(r0 + rt * 16 + ln) * D_DIM + ks * 32 + quad * 8];

    const bool tail = (r0 + 32 > M);

    // Streamed B (queries) + per-lane threshold for PASS2.
    auto load_q = [&](bf16x8 (&bq)[4], float& tv, int qt) {
        const unsigned short* p = &zb[(size_t)(q0 + qt * 16 + ln) * D_DIM + quad * 8];
        #pragma unroll
        for (int ks = 0; ks < 4; ++ks) bq[ks] = *(const bf16x8*)(p + ks * 32);
        if (PASS == 2) tv = T[q0 + qt * 16 + ln];
    };

    auto compute = [&](const bf16x8 (&bq)[4], float tv, int qt) {
        f32x4 acc[2];
        acc[0] = (f32x4){0.f, 0.f, 0.f, 0.f};
        acc[1] = (f32x4){0.f, 0.f, 0.f, 0.f};
        #pragma unroll
        for (int ks = 0; ks < 4; ++ks)
            #pragma unroll
            for (int rt = 0; rt < 2; ++rt)
                acc[rt] = __builtin_amdgcn_mfma_f32_16x16x32_bf16(
                    arf[rt][ks], bq[ks], acc[rt], 0, 0, 0);
        // D[m=ref r0+rt*16+quad*4+ri][n=query q0+qt*16+ln]
        if (PASS == 1) {
            float m;
            if (!tail) {
                m = fmaxf(fmaxf(fmaxf(acc[0][0], acc[0][1]), fmaxf(acc[0][2], acc[0][3])),
                          fmaxf(fmaxf(acc[1][0], acc[1][1]), fmaxf(acc[1][2], acc[1][3])));
            } else {
                m = -3.0f;
                #pragma unroll
                for (int rt = 0; rt < 2; ++rt)
                    #pragma unroll
                    for (int ri = 0; ri < 4; ++ri) {
                        int g = r0 + rt * 16 + quad * 4 + ri;
                        if (g < M) m = fmaxf(m, acc[rt][ri]);
                    }
            }
            m = fmaxf(m, __shfl_xor(m, 16));   // reduce across quads
            m = fmaxf(m, __shfl_xor(m, 32));
            if (lane < 16) mbuf[qt * 16 + ln] = m;
        } else {
            #pragma unroll
            for (int rt = 0; rt < 2; ++rt)
                #pragma unroll
                for (int ri = 0; ri < 4; ++ri) {
                    float v = acc[rt][ri];
                    if (v >= tv) {   // rare (~tens of hits per q over all tiles)
                        int g = r0 + rt * 16 + quad * 4 + ri;
                        if (!tail || g < M) {
                            int q = q0 + qt * 16 + ln;
                            int slot = atomicAdd(&cnt[q], 1);
                            if (slot < CAP) surv[(size_t)q * CAP + slot] = v;
                        }
                    }
                }
        }
    };

    // 2-stage ping-pong pipeline, unrolled x2 (niter is even).
    bf16x8 ba[4], bb[4];
    float ta = 0.f, tb = 0.f;
    load_q(ba, ta, 0);
    for (int qt = 0; qt < niter; qt += 2) {
        if (qt + 1 < niter) load_q(bb, tb, qt + 1);
        compute(ba, ta, qt);
        if (qt + 2 < niter) load_q(ba, ta, qt + 2);
        compute(bb, tb, qt + 1);
    }

    if (PASS == 1) {
        // Coalesced col-major writeout: maxes[ti][q] = subset max.
        #pragma unroll
        for (int i = 0; i < 16; ++i) {
            float v = mbuf[i * 64 + lane];
            maxes[(size_t)ti * N + q0 + i * 64 + lane] = v;
        }
    }
}

// One wave per 64 queries (lane = q). Group ref-tiles by ti%64; group max is a
// real dot, so the (k+1)-th largest of the 64 group maxes is a valid lower
// bound on the true (k+1)-th largest dot. Coalesced column reads.
__global__ __launch_bounds__(64) void knn_threshold(
    const float* __restrict__ maxes, const int* __restrict__ kp,
    float* __restrict__ T, int* __restrict__ cnt, int N, int nt32)
{
    const int q = blockIdx.x * 64 + threadIdx.x;
    float bb[KK];
    #pragma unroll
    for (int i = 0; i < KK; ++i) bb[i] = -3.0f;
    for (int g = 0; g < 64; ++g) {
        float gm = -3.0f;
        #pragma unroll 4
        for (int j = g; j < nt32; j += 64)
            gm = fmaxf(gm, maxes[(size_t)j * N + q]);
        insert11(bb, gm);
    }
    const int kk = *kp;            // 10
    T[q] = bb[KK - 1 - kk];        // (k+1)-th largest of the group maxes
    cnt[q] = 0;
}

// 4 rows per block, one wave each. Exact (k+1)-th largest of survivors.
__global__ __launch_bounds__(256) void knn_final(
    const float* __restrict__ surv, const int* __restrict__ cnt,
    const int* __restrict__ kp, float* __restrict__ out)
{
    const int row = blockIdx.x * 4 + (threadIdx.x >> 6);
    const int t = threadIdx.x & 63;
    int c = cnt[row]; if (c > CAP) c = CAP;
    float v[CAP / 64];   // 16
    float lm = -3.0f;
    #pragma unroll
    for (int i = 0; i < CAP / 64; ++i) {
        int idx = t + 64 * i;
        v[i] = (idx < c) ? surv[(size_t)row * CAP + idx] : -3.0f;
        lm = fmaxf(lm, v[i]);
    }
    const int kk = *kp;
    float cur = -3.0f;
    for (int it = 0; it <= kk; ++it) {
        float m = lm;
        #pragma unroll
        for (int off = 32; off > 0; off >>= 1) m = fmaxf(m, __shfl_xor(m, off));
        cur = m;
        unsigned long long b = __ballot(lm == m);
        if ((int)(__ffsll(b) - 1) == t) {
            bool rm = false;
            lm = -3.0f;
            #pragma unroll
            for (int i = 0; i < CAP / 64; ++i) {
                if (!rm && v[i] == m) { v[i] = -3.0f; rm = true; }
                lm = fmaxf(lm, v[i]);
            }
        }
    }
    if (t == 0) out[row] = sqrtf(fmaxf(2.0f - 2.0f * cur, 1e-12f));
}

extern "C" void kernel_launch(void* const* d_in, const int* in_sizes, int n_in,
                              void* d_out, int out_size, void* d_ws, size_t ws_size,
                              hipStream_t stream) {
    const float* z   = (const float*)d_in[0];
    const float* ref = (const float*)d_in[1];
    const int*   kp  = (const int*)d_in[2];
    float* out = (float*)d_out;

    const int N = in_sizes[0] / D_DIM;   // 2048
    const int M = in_sizes[1] / D_DIM;   // 50000
    const int nt32 = (M + 31) / 32;      // 1563 ref tiles

    unsigned short* zbuf = (unsigned short*)d_ws;             // N*128 bf16 (0.5MB)
    unsigned short* rbuf = zbuf + (size_t)N * D_DIM;          // M*128 bf16 (12.8MB)
    float* maxes = (float*)(rbuf + (size_t)M * D_DIM);        // nt32*N f32 (12.8MB)
    float* T     = maxes + (size_t)nt32 * N;                  // N f32
    int*   cnt   = (int*)(T + N);                             // N i32
    float* surv  = (float*)(cnt + N);                         // N*CAP f32 (8.4MB)

    normalize_bf16<<<(N + M + 3) / 4, 256, 0, stream>>>(z, ref, zbuf, rbuf, N, M);

    const int nblk = nt32 * 2;           // 3126 single-wave blocks (co-resident)

    knn_pass<1><<<nblk, 64, 0, stream>>>(zbuf, rbuf, maxes, nullptr,
                                         nullptr, nullptr, N, M, nt32);
    knn_threshold<<<N / 64, 64, 0, stream>>>(maxes, kp, T, cnt, N, nt32);
    knn_pass<2><<<nblk, 64, 0, stream>>>(zbuf, rbuf, nullptr, T,
                                         cnt, surv, N, M, nt32);
    knn_final<<<N / 4, 256, 0, stream>>>(surv, cnt, kp, out);
}